// Round 21
// baseline (85.188 us; speedup 1.0000x reference)
//
#include <hip/hip_runtime.h>
#include <hip/hip_bf16.h>
#include <math.h>

#define N_TOK 2048
#define DMODEL 1024
#define NHEAD 16
#define DHEAD 64
#define LN_EPS 1e-5f
#define LOG2E 1.44269504f

typedef __attribute__((ext_vector_type(8))) short short8;
typedef __attribute__((ext_vector_type(4))) float f32x4;
typedef __attribute__((ext_vector_type(16))) float f32x16;

__device__ inline unsigned short f2bf(float f) {
    union { float f; unsigned u; } v; v.f = f;
    unsigned r = v.u + 0x7FFF + ((v.u >> 16) & 1);
    return (unsigned short)(r >> 16);
}

__device__ inline float bf2f(unsigned short b) {
    union { unsigned u; float f; } v; v.u = ((unsigned)b) << 16;
    return v.f;
}

__device__ __forceinline__ unsigned cvtpk_bf16(float lo, float hi) {
    unsigned r;
    asm("v_cvt_pk_bf16_f32 %0, %1, %2" : "=v"(r) : "v"(lo), "v"(hi));
    return r;
}

__device__ __forceinline__ float mx3(float a, float b, float c) {
    return fmaxf(fmaxf(a, b), c);   // clang fuses to v_max3_f32
}

__device__ __forceinline__ void gld16(const unsigned short* g, unsigned short* l) {
    __builtin_amdgcn_global_load_lds(
        (const __attribute__((address_space(1))) unsigned int*)g,
        (__attribute__((address_space(3))) unsigned int*)l, 16, 0, 0);
}

// ---------------- merged convert: X, 4 weights -> bf16 ; mask -> madd (log2 dom) ----------------
__global__ __launch_bounds__(256) void cvt_all(
    const float* __restrict__ ht, const float* __restrict__ Wq, const float* __restrict__ Wk,
    const float* __restrict__ Wv, const float* __restrict__ Wd, const float* __restrict__ mask,
    unsigned short* __restrict__ Xb, unsigned short* __restrict__ Wqb,
    unsigned short* __restrict__ Wkb, unsigned short* __restrict__ Wvb,
    unsigned short* __restrict__ Wdb, float* __restrict__ madd)
{
    int b = blockIdx.x;
    if (b < 6144) {
        const float* in; unsigned short* out; int off;
        if (b < 2048) { in = ht; out = Xb; off = b * 1024; }
        else {
            int wb = b - 2048; int wi = wb >> 10;
            off = (wb & 1023) * 1024;
            in  = wi == 0 ? Wq  : wi == 1 ? Wk  : wi == 2 ? Wv  : Wd;
            out = wi == 0 ? Wqb : wi == 1 ? Wkb : wi == 2 ? Wvb : Wdb;
        }
        int i = off + threadIdx.x * 4;
        float4 v = *reinterpret_cast<const float4*>(in + i);
        ushort4 o;
        o.x = f2bf(v.x); o.y = f2bf(v.y); o.z = f2bf(v.z); o.w = f2bf(v.w);
        *reinterpret_cast<ushort4*>(out + i) = o;
    } else {
        int i = (b - 6144) * 1024 + threadIdx.x * 4;
        float4 m = *reinterpret_cast<const float4*>(mask + i);
        float4 o;
        o.x = (1.0f - m.x) * (-10000.0f * LOG2E);
        o.y = (1.0f - m.y) * (-10000.0f * LOG2E);
        o.z = (1.0f - m.z) * (-10000.0f * LOG2E);
        o.w = (1.0f - m.w) * (-10000.0f * LOG2E);
        *reinterpret_cast<float4*>(madd + i) = o;
    }
}

// ---------------- fused QKV GEMM (64x128 tile, BK=128, m97 staging, XCD grid, T2 swizzle) ----------------
// Q output pre-scaled by 0.125*log2(e); V column-blocks write V^T directly.
// BK=128: one stage + one barrier pair covers two 64-wide K sub-tiles (halves drain count).
__global__ __launch_bounds__(256) void gemm_qkv(
    const unsigned short* __restrict__ X,
    const unsigned short* __restrict__ Wq, const unsigned short* __restrict__ Wk,
    const unsigned short* __restrict__ Wv,
    const float* __restrict__ bq, const float* __restrict__ bk, const float* __restrict__ bv,
    unsigned short* __restrict__ Q, unsigned short* __restrict__ K, unsigned short* __restrict__ VT)
{
    __shared__ __align__(16) unsigned short As[64 * 128];    // 16 KB
    __shared__ __align__(16) unsigned short Bs[128 * 128];   // 32 KB; epilogue reuses as [128][72]
    int p = blockIdx.x;
    int work = (p & 7) * 96 + (p >> 3);
    int rowb = work % 32, colb = work / 32;
    int row0 = rowb * 64;
    int col0 = colb * 128;
    int mat = col0 >> 10;
    int wcol0 = col0 & 1023;
    const unsigned short* W = mat == 0 ? Wq : (mat == 1 ? Wk : Wv);
    const float* bias = mat == 0 ? bq : (mat == 1 ? bk : bv);
    float osc = (mat == 0) ? (0.125f * LOG2E) : 1.0f;

    int t = threadIdx.x, w = t >> 6, l = t & 63;
    int lr = l & 15, lk = l >> 4;
    int wc = w * 32;

    f32x4 acc[4][2] = {};

    for (int k0 = 0; k0 < DMODEL; k0 += 128) {
        // As: 16 segments (4 rows x 128 cols each); lane l -> row l>>4, chunk l&15
        #pragma unroll
        for (int c = 0; c < 4; ++c) {
            int ci = (w << 2) | c;                 // 0..15
            int r = ci * 4 + (l >> 4);             // 0..63
            int sch = (((l & 15) ^ (r & 7)) << 3); // T2 pre-swizzled source chunk
            gld16(X + (size_t)(row0 + r) * DMODEL + k0 + sch, As + ci * 512);
        }
        // Bs: 32 segments
        #pragma unroll
        for (int c = 0; c < 8; ++c) {
            int ci = (w << 3) | c;                 // 0..31
            int r = ci * 4 + (l >> 4);             // 0..127
            int sch = (((l & 15) ^ (r & 7)) << 3);
            gld16(W + (size_t)(wcol0 + r) * DMODEL + k0 + sch, Bs + ci * 512);
        }
        __syncthreads();
        #pragma unroll
        for (int kk = 0; kk < 128; kk += 32) {
            short8 af[4], bf[2];
            #pragma unroll
            for (int m = 0; m < 4; ++m)
                af[m] = *reinterpret_cast<const short8*>(
                    As + (m * 16 + lr) * 128 + ((((kk >> 3) + lk) ^ (lr & 7)) << 3));
            #pragma unroll
            for (int n = 0; n < 2; ++n)
                bf[n] = *reinterpret_cast<const short8*>(
                    Bs + (wc + n * 16 + lr) * 128 + ((((kk >> 3) + lk) ^ (lr & 7)) << 3));
            #pragma unroll
            for (int m = 0; m < 4; ++m)
                #pragma unroll
                for (int n = 0; n < 2; ++n)
                    acc[m][n] = __builtin_amdgcn_mfma_f32_16x16x32_bf16(af[m], bf[n], acc[m][n], 0, 0, 0);
        }
        __syncthreads();
    }

    if (mat == 2) {
        // V: transpose via LDS ([128 d][72 pad] view of Bs), write VT[d][n] coalesced
        #pragma unroll
        for (int n = 0; n < 2; ++n) {
            int dl = wc + n * 16 + lr;                 // local d (0..127)
            float bia = bias[wcol0 + dl];
            #pragma unroll
            for (int m = 0; m < 4; ++m) {
                #pragma unroll
                for (int r = 0; r < 4; ++r) {
                    int nl = m * 16 + lk * 4 + r;      // local n (0..63)
                    Bs[dl * 72 + nl] = f2bf(acc[m][n][r] + bia);
                }
            }
        }
        __syncthreads();
        #pragma unroll
        for (int it = 0; it < 4; ++it) {
            int slot = it * 256 + t;                   // 0..1023
            int dl = slot >> 3, nb = slot & 7;
            short8 v = *reinterpret_cast<const short8*>(Bs + dl * 72 + nb * 8);
            *reinterpret_cast<short8*>(VT + (size_t)(wcol0 + dl) * N_TOK + row0 + nb * 8) = v;
        }
    } else {
        unsigned short* O = (mat == 0) ? Q : K;
        #pragma unroll
        for (int n = 0; n < 2; ++n) {
            int ccol = wcol0 + wc + n * 16 + lr;
            float bia = bias[ccol];
            #pragma unroll
            for (int m = 0; m < 4; ++m) {
                #pragma unroll
                for (int r = 0; r < 4; ++r) {
                    int rowg = row0 + m * 16 + lk * 4 + r;
                    O[(size_t)rowg * DMODEL + ccol] = f2bf((acc[m][n][r] + bia) * osc);
                }
            }
        }
    }
}

// ---------------- flash attention: 32x32 MFMA, KVBLK=128 (2 sub-tiles/barrier), XCD grid ----------------
__global__ __launch_bounds__(256) void attn32(
    const unsigned short* __restrict__ Q, const unsigned short* __restrict__ K,
    const unsigned short* __restrict__ VT, const float* __restrict__ madd,
    unsigned short* __restrict__ P0, unsigned short* __restrict__ P1,
    float* __restrict__ Mm, float* __restrict__ Ml)
{
    __shared__ __align__(16) unsigned short Kt[2][2][4096];  // [buf][sub][64 kv][64 dh] swizzled
    __shared__ __align__(16) unsigned short Vt[2][2][4096];  // [buf][sub][64 dh][64 kv] swizzled
    __shared__ __align__(16) float Mt[2][128];               // [buf][kv] mask tile

    int p = blockIdx.x;
    int work = (p & 7) * 64 + (p >> 3);
    int h = (work >> 4) & 15;
    int hb = h * DHEAD;
    int z = work >> 8;
    int kbase = z << 10;
    int t = threadIdx.x, w = t >> 6, l = t & 63;
    int lo5 = l & 31, hi = l >> 5;
    int qw = (work & 15) * 128 + w * 32;

    // Q fragments (B-operand of QK), pre-scaled by 0.125*log2e
    short8 qf[4];
    #pragma unroll
    for (int ds = 0; ds < 4; ++ds)
        qf[ds] = *reinterpret_cast<const short8*>(
            Q + (size_t)(qw + lo5) * DMODEL + hb + ds * 16 + hi * 8);

    short8 ones8;
    #pragma unroll
    for (int j = 0; j < 8; ++j) ones8[j] = (short)0x3F80;  // bf16 1.0

    f32x16 ctx0 = {}, ctx1 = {}, ctxS = {};
    float mrow = -1e30f;

#define STAGE(kt_, buf_) do {                                                   \
        int k0s = kbase + (kt_) * 128;                                          \
        _Pragma("unroll")                                                       \
        for (int sub = 0; sub < 2; ++sub) {                                     \
            _Pragma("unroll")                                                   \
            for (int c = 0; c < 2; ++c) {                                       \
                int ci = (w << 1) | c;                                          \
                int rr = (ci << 3) | (l >> 3);                                  \
                int sc = (((l & 7) ^ (rr & 7)) << 3);                           \
                gld16(K + (size_t)(k0s + sub * 64 + rr) * DMODEL + hb + sc,     \
                      &Kt[buf_][sub][ci * 512]);                                \
                gld16(VT + (size_t)(hb + rr) * N_TOK + k0s + sub * 64 + sc,     \
                      &Vt[buf_][sub][ci * 512]);                                \
            }                                                                   \
        }                                                                       \
        if (t < 32) gld16((const unsigned short*)(madd + k0s + l * 4),          \
                          (unsigned short*)&Mt[buf_][0]);                       \
    } while (0)

    STAGE(0, 0);
    __syncthreads();

    int cb = 0;
    for (int kt = 0; kt < 8; ++kt) {
        if (kt + 1 < 8) STAGE(kt + 1, cb ^ 1);

        #pragma unroll
        for (int sub = 0; sub < 2; ++sub) {
            const unsigned short* Kc = &Kt[cb][sub][0];
            const unsigned short* Vc = &Vt[cb][sub][0];
            const float* Mc = &Mt[cb][sub * 64];

            // S accumulator init = mask (log2 domain) via LDS broadcast reads
            f32x16 s0, s1;
            #pragma unroll
            for (int rg = 0; rg < 4; ++rg) {
                f32x4 a = *reinterpret_cast<const f32x4*>(Mc + 8 * rg + 4 * hi);
                f32x4 b = *reinterpret_cast<const f32x4*>(Mc + 32 + 8 * rg + 4 * hi);
                #pragma unroll
                for (int j = 0; j < 4; ++j) { s0[4 * rg + j] = a[j]; s1[4 * rg + j] = b[j]; }
            }

            // S^T = K Q^T + mask-init (two 32x32 blocks over kv); lane: q = lo5
            __builtin_amdgcn_s_setprio(1);
            #pragma unroll
            for (int ds = 0; ds < 4; ++ds) {
                short8 a0 = *reinterpret_cast<const short8*>(
                    Kc + (size_t)lo5 * 64 + (((2 * ds + hi) ^ (l & 7)) << 3));
                s0 = __builtin_amdgcn_mfma_f32_32x32x16_bf16(a0, qf[ds], s0, 0, 0, 0);
            }
            #pragma unroll
            for (int ds = 0; ds < 4; ++ds) {
                short8 a1 = *reinterpret_cast<const short8*>(
                    Kc + (size_t)(32 + lo5) * 64 + (((2 * ds + hi) ^ (l & 7)) << 3));
                s1 = __builtin_amdgcn_mfma_f32_32x32x16_bf16(a1, qf[ds], s1, 0, 0, 0);
            }
            __builtin_amdgcn_s_setprio(0);

            // row max via max3 tree
            float u0 = mx3(s0[0], s0[1], s0[2]);
            float u1 = mx3(s0[3], s0[4], s0[5]);
            float u2 = mx3(s0[6], s0[7], s0[8]);
            float u3 = mx3(s0[9], s0[10], s0[11]);
            float u4 = mx3(s0[12], s0[13], s0[14]);
            float u5 = mx3(s0[15], s1[0], s1[1]);
            float u6 = mx3(s1[2], s1[3], s1[4]);
            float u7 = mx3(s1[5], s1[6], s1[7]);
            float u8 = mx3(s1[8], s1[9], s1[10]);
            float u9 = mx3(s1[11], s1[12], s1[13]);
            float ua = fmaxf(s1[14], s1[15]);
            float v0_ = mx3(u0, u1, u2);
            float v1_ = mx3(u3, u4, u5);
            float v2_ = mx3(u6, u7, u8);
            float tm = mx3(v0_, v1_, mx3(v2_, u9, ua));
            tm = fmaxf(tm, __shfl_xor(tm, 32));

            if (__any(tm > mrow + 8.0f)) {          // defer-max rescale
                float mnew = fmaxf(mrow, tm);
                float sc = __builtin_amdgcn_exp2f(mrow - mnew);
                mrow = mnew;
                #pragma unroll
                for (int reg = 0; reg < 16; ++reg) {
                    float scr = __shfl(sc, (reg & 3) + 8 * (reg >> 2) + 4 * hi);
                    ctx0[reg] *= scr; ctx1[reg] *= scr; ctxS[reg] *= scr;
                }
            }

            // P = exp2(S - m) packed to bf16 pairs
            unsigned u[2][4][2];
            #pragma unroll
            for (int g = 0; g < 4; ++g) {
                float p0 = __builtin_amdgcn_exp2f(s0[4 * g + 0] - mrow);
                float p1 = __builtin_amdgcn_exp2f(s0[4 * g + 1] - mrow);
                float p2 = __builtin_amdgcn_exp2f(s0[4 * g + 2] - mrow);
                float p3 = __builtin_amdgcn_exp2f(s0[4 * g + 3] - mrow);
                u[0][g][0] = cvtpk_bf16(p0, p1);
                u[0][g][1] = cvtpk_bf16(p2, p3);
                float q0_ = __builtin_amdgcn_exp2f(s1[4 * g + 0] - mrow);
                float q1_ = __builtin_amdgcn_exp2f(s1[4 * g + 1] - mrow);
                float q2_ = __builtin_amdgcn_exp2f(s1[4 * g + 2] - mrow);
                float q3_ = __builtin_amdgcn_exp2f(s1[4 * g + 3] - mrow);
                u[1][g][0] = cvtpk_bf16(q0_, q1_);
                u[1][g][1] = cvtpk_bf16(q2_, q3_);
            }

            // redistribute to A-frag layout: pa[ks] elem j <-> k = 16ks + 8hi + j
            short8 pa[4];
            #pragma unroll
            for (int nb = 0; nb < 2; ++nb) {
                #pragma unroll
                for (int ks = 0; ks < 2; ++ks) {
                    auto r0 = __builtin_amdgcn_permlane32_swap(u[nb][2 * ks][0], u[nb][2 * ks + 1][0], false, false);
                    auto r1 = __builtin_amdgcn_permlane32_swap(u[nb][2 * ks][1], u[nb][2 * ks + 1][1], false, false);
                    union { unsigned uu[4]; short8 v; } pu;
                    pu.uu[0] = r0[0]; pu.uu[1] = r1[0]; pu.uu[2] = r0[1]; pu.uu[3] = r1[1];
                    pa[nb * 2 + ks] = pu.v;
                }
            }

            // ctx += P @ V ; ctxS += P @ 1
            __builtin_amdgcn_s_setprio(1);
            #pragma unroll
            for (int ks = 0; ks < 4; ++ks) {
                short8 v0 = *reinterpret_cast<const short8*>(
                    Vc + (size_t)lo5 * 64 + (((2 * ks + hi) ^ (l & 7)) << 3));
                ctx0 = __builtin_amdgcn_mfma_f32_32x32x16_bf16(pa[ks], v0, ctx0, 0, 0, 0);
                short8 v1 = *reinterpret_cast<const short8*>(
                    Vc + (size_t)(32 + lo5) * 64 + (((2 * ks + hi) ^ (l & 7)) << 3));
                ctx1 = __builtin_amdgcn_mfma_f32_32x32x16_bf16(pa[ks], v1, ctx1, 0, 0, 0);
                ctxS = __builtin_amdgcn_mfma_f32_32x32x16_bf16(pa[ks], ones8, ctxS, 0, 0, 0);
            }
            __builtin_amdgcn_s_setprio(0);
        }

        __syncthreads();
        cb ^= 1;
    }
#undef STAGE

    // epilogue: normalized partials + (m, l)
    unsigned short* P = z ? P1 : P0;
    #pragma unroll
    for (int reg = 0; reg < 16; ++reg) {
        float inv = 1.0f / ctxS[reg];
        int row = qw + (reg & 3) + 8 * (reg >> 2) + 4 * hi;
        P[(size_t)row * DMODEL + hb + lo5]      = f2bf(ctx0[reg] * inv);
        P[(size_t)row * DMODEL + hb + 32 + lo5] = f2bf(ctx1[reg] * inv);
    }
    int mlb = z * (NHEAD * N_TOK) + h * N_TOK + qw;
    if (l < 32) Mm[mlb + l] = mrow;
    #pragma unroll
    for (int reg = 0; reg < 16; ++reg) {
        int q = (reg & 3) + 8 * (reg >> 2) + 4 * hi;
        if (lo5 == reg) Ml[mlb + q] = ctxS[reg];
    }
}

// ---------------- combine the two KV halves (m in log2 domain) ----------------
__global__ __launch_bounds__(256) void attn_combine(
    const unsigned short* __restrict__ P0, const unsigned short* __restrict__ P1,
    const float* __restrict__ Mm, const float* __restrict__ Ml,
    unsigned short* __restrict__ Ctx)
{
    int tok = blockIdx.x;
    int t = threadIdx.x;
    int d = t * 4;
    int h = t >> 4;
    int i0 = h * N_TOK + tok;
    int i1 = NHEAD * N_TOK + i0;
    float m0 = Mm[i0], m1 = Mm[i1];
    float l0 = Ml[i0], l1 = Ml[i1];
    float m = fmaxf(m0, m1);
    float w0 = l0 * __builtin_amdgcn_exp2f(m0 - m);
    float w1 = l1 * __builtin_amdgcn_exp2f(m1 - m);
    float inv = 1.0f / (w0 + w1);
    w0 *= inv; w1 *= inv;
    ushort4 c0 = *reinterpret_cast<const ushort4*>(P0 + (size_t)tok * DMODEL + d);
    ushort4 c1 = *reinterpret_cast<const ushort4*>(P1 + (size_t)tok * DMODEL + d);
    ushort4 o;
    o.x = f2bf(bf2f(c0.x) * w0 + bf2f(c1.x) * w1);
    o.y = f2bf(bf2f(c0.y) * w0 + bf2f(c1.y) * w1);
    o.z = f2bf(bf2f(c0.z) * w0 + bf2f(c1.z) * w1);
    o.w = f2bf(bf2f(c0.w) * w0 + bf2f(c1.w) * w1);
    *reinterpret_cast<ushort4*>(Ctx + (size_t)tok * DMODEL + d) = o;
}

// ---------------- dense + tanh + residual (64x64 tile, XCD grid, T2 LDS swizzle) ----------------
__global__ __launch_bounds__(256) void gemm_dense(
    const unsigned short* __restrict__ X, const unsigned short* __restrict__ W,
    const float* __restrict__ bias, const float* __restrict__ ht,
    float* __restrict__ Sht)
{
    __shared__ __align__(16) unsigned short As[64 * 64];
    __shared__ __align__(16) unsigned short Bs[64 * 64];
    int p = blockIdx.x;
    int work = (p & 7) * 64 + (p >> 3);
    int row0 = (work % 32) * 64;
    int col0 = (work / 32) * 64;

    int t = threadIdx.x, w = t >> 6, l = t & 63;
    int lr = l & 15, lk = l >> 4;
    int wc = w * 16;
    int srow = l >> 3;
    int ssc = (((l & 7) ^ srow) << 3);     // T2: pre-swizzled source column chunk

    f32x4 acc[4] = {};

    for (int k0 = 0; k0 < DMODEL; k0 += 64) {
        #pragma unroll
        for (int c = 0; c < 2; ++c) {
            int ci = (w << 1) | c;
            int r = (ci << 3) | srow;
            gld16(X + (size_t)(row0 + r) * DMODEL + k0 + ssc, As + ci * 512);
            gld16(W + (size_t)(col0 + r) * DMODEL + k0 + ssc, Bs + ci * 512);
        }
        __syncthreads();
        #pragma unroll
        for (int kk = 0; kk < 64; kk += 32) {
            short8 af[4], bf0;
            #pragma unroll
            for (int m = 0; m < 4; ++m)
                af[m] = *reinterpret_cast<const short8*>(
                    As + (m * 16 + lr) * 64 + ((((kk >> 3) + lk) ^ (lr & 7)) << 3));
            bf0 = *reinterpret_cast<const short8*>(
                Bs + (wc + lr) * 64 + ((((kk >> 3) + lk) ^ (lr & 7)) << 3));
            #pragma unroll
            for (int m = 0; m < 4; ++m)
                acc[m] = __builtin_amdgcn_mfma_f32_16x16x32_bf16(af[m], bf0, acc[m], 0, 0, 0);
        }
        __syncthreads();
    }

    int col = col0 + wc + lr;
    float bia = bias[col];
    #pragma unroll
    for (int m = 0; m < 4; ++m) {
        #pragma unroll
        for (int r = 0; r < 4; ++r) {
            int rowg = row0 + m * 16 + lk * 4 + r;
            float x2 = 2.0f * (acc[m][r] + bia);
            float th = 1.0f - 2.0f / (1.0f + __expf(x2));
            Sht[(size_t)rowg * DMODEL + col] = th + ht[(size_t)rowg * DMODEL + col];
        }
    }
}

// ---------------- layernorm ----------------
__global__ __launch_bounds__(256) void layernorm(
    const float* __restrict__ S, const float* __restrict__ gamma,
    const float* __restrict__ beta, float* __restrict__ out)
{
    int row = blockIdx.x;
    int t = threadIdx.x;
    const float* x = S + (size_t)row * DMODEL;
    float4 v = *reinterpret_cast<const float4*>(x + t * 4);
    float sum = v.x + v.y + v.z + v.w;
    float sq = v.x * v.x + v.y * v.y + v.z * v.z + v.w * v.w;
    #pragma unroll
    for (int d = 1; d < 64; d <<= 1) { sum += __shfl_xor(sum, d); sq += __shfl_xor(sq, d); }
    __shared__ float ssum[4], ssq[4];
    int w = t >> 6, l = t & 63;
    if (l == 0) { ssum[w] = sum; ssq[w] = sq; }
    __syncthreads();
    sum = ssum[0] + ssum[1] + ssum[2] + ssum[3];
    sq = ssq[0] + ssq[1] + ssq[2] + ssq[3];
    float mu = sum / DMODEL;
    float var = sq / DMODEL - mu * mu;
    float inv = rsqrtf(var + LN_EPS);
    float4 g = *reinterpret_cast<const float4*>(gamma + t * 4);
    float4 b = *reinterpret_cast<const float4*>(beta + t * 4);
    float4 o;
    o.x = (v.x - mu) * inv * g.x + b.x;
    o.y = (v.y - mu) * inv * g.y + b.y;
    o.z = (v.z - mu) * inv * g.z + b.z;
    o.w = (v.w - mu) * inv * g.w + b.w;
    *reinterpret_cast<float4*>(out + (size_t)row * DMODEL + t * 4) = o;
}

extern "C" void kernel_launch(void* const* d_in, const int* in_sizes, int n_in,
                              void* d_out, int out_size, void* d_ws, size_t ws_size,
                              hipStream_t stream) {
    const float* ht   = (const float*)d_in[0];
    const float* mask = (const float*)d_in[1];
    const float* Wq   = (const float*)d_in[2];
    const float* bq   = (const float*)d_in[3];
    const float* Wk   = (const float*)d_in[4];
    const float* bk   = (const float*)d_in[5];
    const float* Wv   = (const float*)d_in[6];
    const float* bv   = (const float*)d_in[7];
    const float* Wd   = (const float*)d_in[8];
    const float* bd   = (const float*)d_in[9];
    const float* gamma= (const float*)d_in[10];
    const float* beta = (const float*)d_in[11];
    float* out = (float*)d_out;

    char* ws = (char*)d_ws;
    const size_t MB = 1024 * 1024;
    unsigned short* Xb  = (unsigned short*)(ws + 0 * MB);   // 4 MB (dead after qkv -> Pctx0)
    unsigned short* Wqb = (unsigned short*)(ws + 4 * MB);   // 2 MB each (dead after qkv -> Mm/Ml)
    unsigned short* Wkb = (unsigned short*)(ws + 6 * MB);
    unsigned short* Wvb = (unsigned short*)(ws + 8 * MB);
    unsigned short* Wdb = (unsigned short*)(ws + 10 * MB);
    unsigned short* Qb  = (unsigned short*)(ws + 12 * MB);  // 4 MB
    unsigned short* Kb  = (unsigned short*)(ws + 16 * MB);  // 4 MB
    unsigned short* Vb  = (unsigned short*)(ws + 20 * MB);  // 4 MB scratch (-> Pctx1)
    unsigned short* VTb = (unsigned short*)(ws + 24 * MB);  // 4 MB (written by gemm_qkv directly)
    unsigned short* Ctxb= (unsigned short*)(ws + 28 * MB);  // 4 MB
    float* maddb        = (float*)(ws + 32 * MB);           // 8 KB
    unsigned short* Pctx0 = Xb;                             // partial ctx half 0
    unsigned short* Pctx1 = Vb;                             // partial ctx half 1
    float* Mm           = (float*)(ws + 4 * MB);            // 256 KB
    float* Ml           = (float*)(ws + 4 * MB + 256 * 1024); // 256 KB
    float* Sht          = (float*)(ws + 12 * MB);           // 8 MB, overlays Qb/Kb

    cvt_all<<<6146, 256, 0, stream>>>(ht, Wq, Wk, Wv, Wd, mask,
                                      Xb, Wqb, Wkb, Wvb, Wdb, maddb);

    gemm_qkv<<<768, 256, 0, stream>>>(Xb, Wqb, Wkb, Wvb, bq, bk, bv, Qb, Kb, VTb);

    attn32<<<512, 256, 0, stream>>>(Qb, Kb, VTb, maddb, Pctx0, Pctx1, Mm, Ml);

    attn_combine<<<N_TOK, 256, 0, stream>>>(Pctx0, Pctx1, Mm, Ml, Ctxb);

    gemm_dense<<<512, 256, 0, stream>>>(Ctxb, Wdb, bd, ht, Sht);

    layernorm<<<N_TOK, 256, 0, stream>>>(Sht, gamma, beta, out);
}

// Round 22
// 84.154 us; speedup vs baseline: 1.0123x; 1.0123x over previous
//
#include <hip/hip_runtime.h>
#include <hip/hip_bf16.h>
#include <math.h>

#define N_TOK 2048
#define DMODEL 1024
#define NHEAD 16
#define DHEAD 64
#define LN_EPS 1e-5f
#define LOG2E 1.44269504f

typedef __attribute__((ext_vector_type(8))) short short8;
typedef __attribute__((ext_vector_type(4))) float f32x4;
typedef __attribute__((ext_vector_type(16))) float f32x16;

__device__ inline unsigned short f2bf(float f) {
    union { float f; unsigned u; } v; v.f = f;
    unsigned r = v.u + 0x7FFF + ((v.u >> 16) & 1);
    return (unsigned short)(r >> 16);
}

__device__ inline float bf2f(unsigned short b) {
    union { unsigned u; float f; } v; v.u = ((unsigned)b) << 16;
    return v.f;
}

__device__ __forceinline__ unsigned cvtpk_bf16(float lo, float hi) {
    unsigned r;
    asm("v_cvt_pk_bf16_f32 %0, %1, %2" : "=v"(r) : "v"(lo), "v"(hi));
    return r;
}

__device__ __forceinline__ float mx3(float a, float b, float c) {
    return fmaxf(fmaxf(a, b), c);   // clang fuses to v_max3_f32
}

__device__ __forceinline__ void gld16(const unsigned short* g, unsigned short* l) {
    __builtin_amdgcn_global_load_lds(
        (const __attribute__((address_space(1))) unsigned int*)g,
        (__attribute__((address_space(3))) unsigned int*)l, 16, 0, 0);
}

// ---------------- merged convert: X, 4 weights -> bf16 ; mask -> madd (log2 dom) ----------------
__global__ __launch_bounds__(256) void cvt_all(
    const float* __restrict__ ht, const float* __restrict__ Wq, const float* __restrict__ Wk,
    const float* __restrict__ Wv, const float* __restrict__ Wd, const float* __restrict__ mask,
    unsigned short* __restrict__ Xb, unsigned short* __restrict__ Wqb,
    unsigned short* __restrict__ Wkb, unsigned short* __restrict__ Wvb,
    unsigned short* __restrict__ Wdb, float* __restrict__ madd)
{
    int b = blockIdx.x;
    if (b < 6144) {
        const float* in; unsigned short* out; int off;
        if (b < 2048) { in = ht; out = Xb; off = b * 1024; }
        else {
            int wb = b - 2048; int wi = wb >> 10;
            off = (wb & 1023) * 1024;
            in  = wi == 0 ? Wq  : wi == 1 ? Wk  : wi == 2 ? Wv  : Wd;
            out = wi == 0 ? Wqb : wi == 1 ? Wkb : wi == 2 ? Wvb : Wdb;
        }
        int i = off + threadIdx.x * 4;
        float4 v = *reinterpret_cast<const float4*>(in + i);
        ushort4 o;
        o.x = f2bf(v.x); o.y = f2bf(v.y); o.z = f2bf(v.z); o.w = f2bf(v.w);
        *reinterpret_cast<ushort4*>(out + i) = o;
    } else {
        int i = (b - 6144) * 1024 + threadIdx.x * 4;
        float4 m = *reinterpret_cast<const float4*>(mask + i);
        float4 o;
        o.x = (1.0f - m.x) * (-10000.0f * LOG2E);
        o.y = (1.0f - m.y) * (-10000.0f * LOG2E);
        o.z = (1.0f - m.z) * (-10000.0f * LOG2E);
        o.w = (1.0f - m.w) * (-10000.0f * LOG2E);
        *reinterpret_cast<float4*>(madd + i) = o;
    }
}

// ---------------- fused QKV GEMM (64x128 tile, m97 staging, XCD grid, T2 LDS swizzle) ----------------
// Q output pre-scaled by 0.125*log2(e); V column-blocks write V^T directly.
__global__ __launch_bounds__(256) void gemm_qkv(
    const unsigned short* __restrict__ X,
    const unsigned short* __restrict__ Wq, const unsigned short* __restrict__ Wk,
    const unsigned short* __restrict__ Wv,
    const float* __restrict__ bq, const float* __restrict__ bk, const float* __restrict__ bv,
    unsigned short* __restrict__ Q, unsigned short* __restrict__ K, unsigned short* __restrict__ VT)
{
    __shared__ __align__(16) unsigned short As[64 * 64];
    __shared__ __align__(16) unsigned short Bs[128 * 72];   // main loop uses first 128*64; epilogue [128][72]
    int p = blockIdx.x;
    int work = (p & 7) * 96 + (p >> 3);
    int rowb = work % 32, colb = work / 32;
    int row0 = rowb * 64;
    int col0 = colb * 128;
    int mat = col0 >> 10;
    int wcol0 = col0 & 1023;
    const unsigned short* W = mat == 0 ? Wq : (mat == 1 ? Wk : Wv);
    const float* bias = mat == 0 ? bq : (mat == 1 ? bk : bv);
    float osc = (mat == 0) ? (0.125f * LOG2E) : 1.0f;

    int t = threadIdx.x, w = t >> 6, l = t & 63;
    int lr = l & 15, lk = l >> 4;
    int wc = w * 32;
    int srow = l >> 3;
    int ssc = (((l & 7) ^ srow) << 3);     // T2: pre-swizzled source column chunk

    f32x4 acc[4][2] = {};

    for (int k0 = 0; k0 < DMODEL; k0 += 64) {
        #pragma unroll
        for (int c = 0; c < 2; ++c) {
            int ci = (w << 1) | c;
            int r = (ci << 3) | srow;
            gld16(X + (size_t)(row0 + r) * DMODEL + k0 + ssc, As + ci * 512);
        }
        #pragma unroll
        for (int c = 0; c < 4; ++c) {
            int ci = (w << 2) | c;
            int r = (ci << 3) | srow;
            gld16(W + (size_t)(wcol0 + r) * DMODEL + k0 + ssc, Bs + ci * 512);
        }
        __syncthreads();
        #pragma unroll
        for (int kk = 0; kk < 64; kk += 32) {
            short8 af[4], bf[2];
            #pragma unroll
            for (int m = 0; m < 4; ++m)
                af[m] = *reinterpret_cast<const short8*>(
                    As + (m * 16 + lr) * 64 + ((((kk >> 3) + lk) ^ (lr & 7)) << 3));
            #pragma unroll
            for (int n = 0; n < 2; ++n)
                bf[n] = *reinterpret_cast<const short8*>(
                    Bs + (wc + n * 16 + lr) * 64 + ((((kk >> 3) + lk) ^ (lr & 7)) << 3));
            #pragma unroll
            for (int m = 0; m < 4; ++m)
                #pragma unroll
                for (int n = 0; n < 2; ++n)
                    acc[m][n] = __builtin_amdgcn_mfma_f32_16x16x32_bf16(af[m], bf[n], acc[m][n], 0, 0, 0);
        }
        __syncthreads();
    }

    if (mat == 2) {
        // V: transpose via LDS ([128 d][72 pad] view of Bs), write VT[d][n] coalesced
        #pragma unroll
        for (int n = 0; n < 2; ++n) {
            int dl = wc + n * 16 + lr;                 // local d (0..127)
            float bia = bias[wcol0 + dl];
            #pragma unroll
            for (int m = 0; m < 4; ++m) {
                #pragma unroll
                for (int r = 0; r < 4; ++r) {
                    int nl = m * 16 + lk * 4 + r;      // local n (0..63)
                    Bs[dl * 72 + nl] = f2bf(acc[m][n][r] + bia);
                }
            }
        }
        __syncthreads();
        #pragma unroll
        for (int it = 0; it < 4; ++it) {
            int slot = it * 256 + t;                   // 0..1023
            int dl = slot >> 3, nb = slot & 7;
            short8 v = *reinterpret_cast<const short8*>(Bs + dl * 72 + nb * 8);
            *reinterpret_cast<short8*>(VT + (size_t)(wcol0 + dl) * N_TOK + row0 + nb * 8) = v;
        }
    } else {
        unsigned short* O = (mat == 0) ? Q : K;
        #pragma unroll
        for (int n = 0; n < 2; ++n) {
            int ccol = wcol0 + wc + n * 16 + lr;
            float bia = bias[ccol];
            #pragma unroll
            for (int m = 0; m < 4; ++m) {
                #pragma unroll
                for (int r = 0; r < 4; ++r) {
                    int rowg = row0 + m * 16 + lk * 4 + r;
                    O[(size_t)rowg * DMODEL + ccol] = f2bf((acc[m][n][r] + bia) * osc);
                }
            }
        }
    }
}

// ---------------- flash attention: 32x32 MFMA, KVBLK=128 (2 sub-tiles/barrier), XCD grid ----------------
__global__ __launch_bounds__(256) void attn32(
    const unsigned short* __restrict__ Q, const unsigned short* __restrict__ K,
    const unsigned short* __restrict__ VT, const float* __restrict__ madd,
    unsigned short* __restrict__ P0, unsigned short* __restrict__ P1,
    float* __restrict__ Mm, float* __restrict__ Ml)
{
    __shared__ __align__(16) unsigned short Kt[2][2][4096];  // [buf][sub][64 kv][64 dh] swizzled
    __shared__ __align__(16) unsigned short Vt[2][2][4096];  // [buf][sub][64 dh][64 kv] swizzled
    __shared__ __align__(16) float Mt[2][128];               // [buf][kv] mask tile

    int p = blockIdx.x;
    int work = (p & 7) * 64 + (p >> 3);
    int h = (work >> 4) & 15;
    int hb = h * DHEAD;
    int z = work >> 8;
    int kbase = z << 10;
    int t = threadIdx.x, w = t >> 6, l = t & 63;
    int lo5 = l & 31, hi = l >> 5;
    int qw = (work & 15) * 128 + w * 32;

    // Q fragments (B-operand of QK), pre-scaled by 0.125*log2e
    short8 qf[4];
    #pragma unroll
    for (int ds = 0; ds < 4; ++ds)
        qf[ds] = *reinterpret_cast<const short8*>(
            Q + (size_t)(qw + lo5) * DMODEL + hb + ds * 16 + hi * 8);

    short8 ones8;
    #pragma unroll
    for (int j = 0; j < 8; ++j) ones8[j] = (short)0x3F80;  // bf16 1.0

    f32x16 ctx0 = {}, ctx1 = {}, ctxS = {};
    float mrow = -1e30f;

#define STAGE(kt_, buf_) do {                                                   \
        int k0s = kbase + (kt_) * 128;                                          \
        _Pragma("unroll")                                                       \
        for (int sub = 0; sub < 2; ++sub) {                                     \
            _Pragma("unroll")                                                   \
            for (int c = 0; c < 2; ++c) {                                       \
                int ci = (w << 1) | c;                                          \
                int rr = (ci << 3) | (l >> 3);                                  \
                int sc = (((l & 7) ^ (rr & 7)) << 3);                           \
                gld16(K + (size_t)(k0s + sub * 64 + rr) * DMODEL + hb + sc,     \
                      &Kt[buf_][sub][ci * 512]);                                \
                gld16(VT + (size_t)(hb + rr) * N_TOK + k0s + sub * 64 + sc,     \
                      &Vt[buf_][sub][ci * 512]);                                \
            }                                                                   \
        }                                                                       \
        if (t < 32) gld16((const unsigned short*)(madd + k0s + l * 4),          \
                          (unsigned short*)&Mt[buf_][0]);                       \
    } while (0)

    STAGE(0, 0);
    __syncthreads();

    int cb = 0;
    for (int kt = 0; kt < 8; ++kt) {
        if (kt + 1 < 8) STAGE(kt + 1, cb ^ 1);

        #pragma unroll
        for (int sub = 0; sub < 2; ++sub) {
            const unsigned short* Kc = &Kt[cb][sub][0];
            const unsigned short* Vc = &Vt[cb][sub][0];
            const float* Mc = &Mt[cb][sub * 64];

            // S accumulator init = mask (log2 domain) via LDS broadcast reads
            f32x16 s0, s1;
            #pragma unroll
            for (int rg = 0; rg < 4; ++rg) {
                f32x4 a = *reinterpret_cast<const f32x4*>(Mc + 8 * rg + 4 * hi);
                f32x4 b = *reinterpret_cast<const f32x4*>(Mc + 32 + 8 * rg + 4 * hi);
                #pragma unroll
                for (int j = 0; j < 4; ++j) { s0[4 * rg + j] = a[j]; s1[4 * rg + j] = b[j]; }
            }

            // S^T = K Q^T + mask-init (two 32x32 blocks over kv); lane: q = lo5
            __builtin_amdgcn_s_setprio(1);
            #pragma unroll
            for (int ds = 0; ds < 4; ++ds) {
                short8 a0 = *reinterpret_cast<const short8*>(
                    Kc + (size_t)lo5 * 64 + (((2 * ds + hi) ^ (l & 7)) << 3));
                s0 = __builtin_amdgcn_mfma_f32_32x32x16_bf16(a0, qf[ds], s0, 0, 0, 0);
            }
            #pragma unroll
            for (int ds = 0; ds < 4; ++ds) {
                short8 a1 = *reinterpret_cast<const short8*>(
                    Kc + (size_t)(32 + lo5) * 64 + (((2 * ds + hi) ^ (l & 7)) << 3));
                s1 = __builtin_amdgcn_mfma_f32_32x32x16_bf16(a1, qf[ds], s1, 0, 0, 0);
            }
            __builtin_amdgcn_s_setprio(0);

            // row max via max3 tree
            float u0 = mx3(s0[0], s0[1], s0[2]);
            float u1 = mx3(s0[3], s0[4], s0[5]);
            float u2 = mx3(s0[6], s0[7], s0[8]);
            float u3 = mx3(s0[9], s0[10], s0[11]);
            float u4 = mx3(s0[12], s0[13], s0[14]);
            float u5 = mx3(s0[15], s1[0], s1[1]);
            float u6 = mx3(s1[2], s1[3], s1[4]);
            float u7 = mx3(s1[5], s1[6], s1[7]);
            float u8 = mx3(s1[8], s1[9], s1[10]);
            float u9 = mx3(s1[11], s1[12], s1[13]);
            float ua = fmaxf(s1[14], s1[15]);
            float v0_ = mx3(u0, u1, u2);
            float v1_ = mx3(u3, u4, u5);
            float v2_ = mx3(u6, u7, u8);
            float tm = mx3(v0_, v1_, mx3(v2_, u9, ua));
            tm = fmaxf(tm, __shfl_xor(tm, 32));

            if (__any(tm > mrow + 8.0f)) {          // defer-max rescale
                float mnew = fmaxf(mrow, tm);
                float sc = __builtin_amdgcn_exp2f(mrow - mnew);
                mrow = mnew;
                #pragma unroll
                for (int reg = 0; reg < 16; ++reg) {
                    float scr = __shfl(sc, (reg & 3) + 8 * (reg >> 2) + 4 * hi);
                    ctx0[reg] *= scr; ctx1[reg] *= scr; ctxS[reg] *= scr;
                }
            }

            // P = exp2(S - m) packed to bf16 pairs
            unsigned u[2][4][2];
            #pragma unroll
            for (int g = 0; g < 4; ++g) {
                float p0 = __builtin_amdgcn_exp2f(s0[4 * g + 0] - mrow);
                float p1 = __builtin_amdgcn_exp2f(s0[4 * g + 1] - mrow);
                float p2 = __builtin_amdgcn_exp2f(s0[4 * g + 2] - mrow);
                float p3 = __builtin_amdgcn_exp2f(s0[4 * g + 3] - mrow);
                u[0][g][0] = cvtpk_bf16(p0, p1);
                u[0][g][1] = cvtpk_bf16(p2, p3);
                float q0_ = __builtin_amdgcn_exp2f(s1[4 * g + 0] - mrow);
                float q1_ = __builtin_amdgcn_exp2f(s1[4 * g + 1] - mrow);
                float q2_ = __builtin_amdgcn_exp2f(s1[4 * g + 2] - mrow);
                float q3_ = __builtin_amdgcn_exp2f(s1[4 * g + 3] - mrow);
                u[1][g][0] = cvtpk_bf16(q0_, q1_);
                u[1][g][1] = cvtpk_bf16(q2_, q3_);
            }

            // redistribute to A-frag layout: pa[ks] elem j <-> k = 16ks + 8hi + j
            short8 pa[4];
            #pragma unroll
            for (int nb = 0; nb < 2; ++nb) {
                #pragma unroll
                for (int ks = 0; ks < 2; ++ks) {
                    auto r0 = __builtin_amdgcn_permlane32_swap(u[nb][2 * ks][0], u[nb][2 * ks + 1][0], false, false);
                    auto r1 = __builtin_amdgcn_permlane32_swap(u[nb][2 * ks][1], u[nb][2 * ks + 1][1], false, false);
                    union { unsigned uu[4]; short8 v; } pu;
                    pu.uu[0] = r0[0]; pu.uu[1] = r1[0]; pu.uu[2] = r0[1]; pu.uu[3] = r1[1];
                    pa[nb * 2 + ks] = pu.v;
                }
            }

            // ctx += P @ V ; ctxS += P @ 1
            __builtin_amdgcn_s_setprio(1);
            #pragma unroll
            for (int ks = 0; ks < 4; ++ks) {
                short8 v0 = *reinterpret_cast<const short8*>(
                    Vc + (size_t)lo5 * 64 + (((2 * ks + hi) ^ (l & 7)) << 3));
                ctx0 = __builtin_amdgcn_mfma_f32_32x32x16_bf16(pa[ks], v0, ctx0, 0, 0, 0);
                short8 v1 = *reinterpret_cast<const short8*>(
                    Vc + (size_t)(32 + lo5) * 64 + (((2 * ks + hi) ^ (l & 7)) << 3));
                ctx1 = __builtin_amdgcn_mfma_f32_32x32x16_bf16(pa[ks], v1, ctx1, 0, 0, 0);
                ctxS = __builtin_amdgcn_mfma_f32_32x32x16_bf16(pa[ks], ones8, ctxS, 0, 0, 0);
            }
            __builtin_amdgcn_s_setprio(0);
        }

        __syncthreads();
        cb ^= 1;
    }
#undef STAGE

    // epilogue: normalized partials + (m, l)
    unsigned short* P = z ? P1 : P0;
    #pragma unroll
    for (int reg = 0; reg < 16; ++reg) {
        float inv = 1.0f / ctxS[reg];
        int row = qw + (reg & 3) + 8 * (reg >> 2) + 4 * hi;
        P[(size_t)row * DMODEL + hb + lo5]      = f2bf(ctx0[reg] * inv);
        P[(size_t)row * DMODEL + hb + 32 + lo5] = f2bf(ctx1[reg] * inv);
    }
    int mlb = z * (NHEAD * N_TOK) + h * N_TOK + qw;
    if (l < 32) Mm[mlb + l] = mrow;
    #pragma unroll
    for (int reg = 0; reg < 16; ++reg) {
        int q = (reg & 3) + 8 * (reg >> 2) + 4 * hi;
        if (lo5 == reg) Ml[mlb + q] = ctxS[reg];
    }
}

// ---------------- combine the two KV halves (m in log2 domain) ----------------
__global__ __launch_bounds__(256) void attn_combine(
    const unsigned short* __restrict__ P0, const unsigned short* __restrict__ P1,
    const float* __restrict__ Mm, const float* __restrict__ Ml,
    unsigned short* __restrict__ Ctx)
{
    int tok = blockIdx.x;
    int t = threadIdx.x;
    int d = t * 4;
    int h = t >> 4;
    int i0 = h * N_TOK + tok;
    int i1 = NHEAD * N_TOK + i0;
    float m0 = Mm[i0], m1 = Mm[i1];
    float l0 = Ml[i0], l1 = Ml[i1];
    float m = fmaxf(m0, m1);
    float w0 = l0 * __builtin_amdgcn_exp2f(m0 - m);
    float w1 = l1 * __builtin_amdgcn_exp2f(m1 - m);
    float inv = 1.0f / (w0 + w1);
    w0 *= inv; w1 *= inv;
    ushort4 c0 = *reinterpret_cast<const ushort4*>(P0 + (size_t)tok * DMODEL + d);
    ushort4 c1 = *reinterpret_cast<const ushort4*>(P1 + (size_t)tok * DMODEL + d);
    ushort4 o;
    o.x = f2bf(bf2f(c0.x) * w0 + bf2f(c1.x) * w1);
    o.y = f2bf(bf2f(c0.y) * w0 + bf2f(c1.y) * w1);
    o.z = f2bf(bf2f(c0.z) * w0 + bf2f(c1.z) * w1);
    o.w = f2bf(bf2f(c0.w) * w0 + bf2f(c1.w) * w1);
    *reinterpret_cast<ushort4*>(Ctx + (size_t)tok * DMODEL + d) = o;
}

// ---------------- dense + tanh + residual (64x64 tile, XCD grid, T2 LDS swizzle) ----------------
__global__ __launch_bounds__(256) void gemm_dense(
    const unsigned short* __restrict__ X, const unsigned short* __restrict__ W,
    const float* __restrict__ bias, const float* __restrict__ ht,
    float* __restrict__ Sht)
{
    __shared__ __align__(16) unsigned short As[64 * 64];
    __shared__ __align__(16) unsigned short Bs[64 * 64];
    int p = blockIdx.x;
    int work = (p & 7) * 64 + (p >> 3);
    int row0 = (work % 32) * 64;
    int col0 = (work / 32) * 64;

    int t = threadIdx.x, w = t >> 6, l = t & 63;
    int lr = l & 15, lk = l >> 4;
    int wc = w * 16;
    int srow = l >> 3;
    int ssc = (((l & 7) ^ srow) << 3);     // T2: pre-swizzled source column chunk

    f32x4 acc[4] = {};

    for (int k0 = 0; k0 < DMODEL; k0 += 64) {
        #pragma unroll
        for (int c = 0; c < 2; ++c) {
            int ci = (w << 1) | c;
            int r = (ci << 3) | srow;
            gld16(X + (size_t)(row0 + r) * DMODEL + k0 + ssc, As + ci * 512);
            gld16(W + (size_t)(col0 + r) * DMODEL + k0 + ssc, Bs + ci * 512);
        }
        __syncthreads();
        #pragma unroll
        for (int kk = 0; kk < 64; kk += 32) {
            short8 af[4], bf0;
            #pragma unroll
            for (int m = 0; m < 4; ++m)
                af[m] = *reinterpret_cast<const short8*>(
                    As + (m * 16 + lr) * 64 + ((((kk >> 3) + lk) ^ (lr & 7)) << 3));
            bf0 = *reinterpret_cast<const short8*>(
                Bs + (wc + lr) * 64 + ((((kk >> 3) + lk) ^ (lr & 7)) << 3));
            #pragma unroll
            for (int m = 0; m < 4; ++m)
                acc[m] = __builtin_amdgcn_mfma_f32_16x16x32_bf16(af[m], bf0, acc[m], 0, 0, 0);
        }
        __syncthreads();
    }

    int col = col0 + wc + lr;
    float bia = bias[col];
    #pragma unroll
    for (int m = 0; m < 4; ++m) {
        #pragma unroll
        for (int r = 0; r < 4; ++r) {
            int rowg = row0 + m * 16 + lk * 4 + r;
            float x2 = 2.0f * (acc[m][r] + bia);
            float th = 1.0f - 2.0f / (1.0f + __expf(x2));
            Sht[(size_t)rowg * DMODEL + col] = th + ht[(size_t)rowg * DMODEL + col];
        }
    }
}

// ---------------- layernorm ----------------
__global__ __launch_bounds__(256) void layernorm(
    const float* __restrict__ S, const float* __restrict__ gamma,
    const float* __restrict__ beta, float* __restrict__ out)
{
    int row = blockIdx.x;
    int t = threadIdx.x;
    const float* x = S + (size_t)row * DMODEL;
    float4 v = *reinterpret_cast<const float4*>(x + t * 4);
    float sum = v.x + v.y + v.z + v.w;
    float sq = v.x * v.x + v.y * v.y + v.z * v.z + v.w * v.w;
    #pragma unroll
    for (int d = 1; d < 64; d <<= 1) { sum += __shfl_xor(sum, d); sq += __shfl_xor(sq, d); }
    __shared__ float ssum[4], ssq[4];
    int w = t >> 6, l = t & 63;
    if (l == 0) { ssum[w] = sum; ssq[w] = sq; }
    __syncthreads();
    sum = ssum[0] + ssum[1] + ssum[2] + ssum[3];
    sq = ssq[0] + ssq[1] + ssq[2] + ssq[3];
    float mu = sum / DMODEL;
    float var = sq / DMODEL - mu * mu;
    float inv = rsqrtf(var + LN_EPS);
    float4 g = *reinterpret_cast<const float4*>(gamma + t * 4);
    float4 b = *reinterpret_cast<const float4*>(beta + t * 4);
    float4 o;
    o.x = (v.x - mu) * inv * g.x + b.x;
    o.y = (v.y - mu) * inv * g.y + b.y;
    o.z = (v.z - mu) * inv * g.z + b.z;
    o.w = (v.w - mu) * inv * g.w + b.w;
    *reinterpret_cast<float4*>(out + (size_t)row * DMODEL + t * 4) = o;
}

extern "C" void kernel_launch(void* const* d_in, const int* in_sizes, int n_in,
                              void* d_out, int out_size, void* d_ws, size_t ws_size,
                              hipStream_t stream) {
    const float* ht   = (const float*)d_in[0];
    const float* mask = (const float*)d_in[1];
    const float* Wq   = (const float*)d_in[2];
    const float* bq   = (const float*)d_in[3];
    const float* Wk   = (const float*)d_in[4];
    const float* bk   = (const float*)d_in[5];
    const float* Wv   = (const float*)d_in[6];
    const float* bv   = (const float*)d_in[7];
    const float* Wd   = (const float*)d_in[8];
    const float* bd   = (const float*)d_in[9];
    const float* gamma= (const float*)d_in[10];
    const float* beta = (const float*)d_in[11];
    float* out = (float*)d_out;

    char* ws = (char*)d_ws;
    const size_t MB = 1024 * 1024;
    unsigned short* Xb  = (unsigned short*)(ws + 0 * MB);   // 4 MB (dead after qkv -> Pctx0)
    unsigned short* Wqb = (unsigned short*)(ws + 4 * MB);   // 2 MB each (dead after qkv -> Mm/Ml)
    unsigned short* Wkb = (unsigned short*)(ws + 6 * MB);
    unsigned short* Wvb = (unsigned short*)(ws + 8 * MB);
    unsigned short* Wdb = (unsigned short*)(ws + 10 * MB);
    unsigned short* Qb  = (unsigned short*)(ws + 12 * MB);  // 4 MB
    unsigned short* Kb  = (unsigned short*)(ws + 16 * MB);  // 4 MB
    unsigned short* Vb  = (unsigned short*)(ws + 20 * MB);  // 4 MB scratch (-> Pctx1)
    unsigned short* VTb = (unsigned short*)(ws + 24 * MB);  // 4 MB (written by gemm_qkv directly)
    unsigned short* Ctxb= (unsigned short*)(ws + 28 * MB);  // 4 MB
    float* maddb        = (float*)(ws + 32 * MB);           // 8 KB
    unsigned short* Pctx0 = Xb;                             // partial ctx half 0
    unsigned short* Pctx1 = Vb;                             // partial ctx half 1
    float* Mm           = (float*)(ws + 4 * MB);            // 256 KB
    float* Ml           = (float*)(ws + 4 * MB + 256 * 1024); // 256 KB
    float* Sht          = (float*)(ws + 12 * MB);           // 8 MB, overlays Qb/Kb

    cvt_all<<<6146, 256, 0, stream>>>(ht, Wq, Wk, Wv, Wd, mask,
                                      Xb, Wqb, Wkb, Wvb, Wdb, maddb);

    gemm_qkv<<<768, 256, 0, stream>>>(Xb, Wqb, Wkb, Wvb, bq, bk, bv, Qb, Kb, VTb);

    attn32<<<512, 256, 0, stream>>>(Qb, Kb, VTb, maddb, Pctx0, Pctx1, Mm, Ml);

    attn_combine<<<N_TOK, 256, 0, stream>>>(Pctx0, Pctx1, Mm, Ml, Ctxb);

    gemm_dense<<<512, 256, 0, stream>>>(Ctxb, Wdb, bd, ht, Sht);

    layernorm<<<N_TOK, 256, 0, stream>>>(Sht, gamma, beta, out);
}